// Round 8
// baseline (299.851 us; speedup 1.0000x reference)
//
#include <hip/hip_runtime.h>
#include <hip/hip_bf16.h>

#define N 8192
#define F 256
#define KSPLIT 4
#define JBLK (N / KSPLIT)    // 2048 cols per k3 block
#define NITER (JBLK / 64)    // 32 j-tiles of 64
#define LOG2E 1.4426950408889634f

using s16x8 = __attribute__((ext_vector_type(8))) short;
using f32x4 = __attribute__((ext_vector_type(4))) float;

static __device__ __forceinline__ unsigned short f2bf(float f) {
  unsigned int u = __float_as_uint(f);
  unsigned int r = u + 0x7fffu + ((u >> 16) & 1u);   // RNE
  return (unsigned short)(r >> 16);
}
static __device__ __forceinline__ float bf2f(unsigned short u) {
  return __uint_as_float(((unsigned int)u) << 16);
}
static __device__ __forceinline__ f32x4 ntl4(const float* p) {
  return __builtin_nontemporal_load(reinterpret_cast<const f32x4*>(p));
}

// ---------------- k0: Wt[f][k] = bf16(W[k][f]) ----------------
__global__ __launch_bounds__(256) void k0_wt(const float* __restrict__ W,
                                             unsigned short* __restrict__ Wt) {
  int k = blockIdx.x;
  int f = threadIdx.x;
  Wt[f * 256 + k] = f2bf(W[k * 256 + f]);
}

// ---------------- k1: Wh GEMM -> tiled/swizzled WhbT + fused s1,s2 (pre-scaled by log2e) ----
// WhbT tiled layout: tile tj (64 j's): byte off = tj*32768 + f*128 + ((jo*16)^((f&7)<<4)) + sub*8
__global__ __launch_bounds__(256) void k1_wh(const float* __restrict__ h,
                                             const unsigned short* __restrict__ Wt,
                                             const float* __restrict__ a,
                                             char* __restrict__ WhbT,
                                             float* __restrict__ s1g,
                                             float* __restrict__ s2g) {
  __shared__ char lds[8192 + 32768];
  char* Alds = lds;
  char* Blds = lds + 8192;
  int t = threadIdx.x;
  int i0 = blockIdx.x * 64;
  int l = t & 63, w = t >> 6;
  int lr = l & 15, lk = l >> 4;
  f32x4 acc[4][4] = {};
  for (int kt = 0; kt < 4; ++kt) {
    int k0 = kt * 64;
    if (kt) __syncthreads();
#pragma unroll
    for (int c = 0; c < 4; ++c) {
      int flat = c * 256 + t;
      int i = flat >> 4, jc = flat & 15;
      float4 v = *reinterpret_cast<const float4*>(h + (size_t)(i0 + i) * 256 + k0 + jc * 4);
      ushort4 pk;
      pk.x = f2bf(v.x); pk.y = f2bf(v.y); pk.z = f2bf(v.z); pk.w = f2bf(v.w);
      *reinterpret_cast<ushort4*>(Alds + i * 128 + ((jc * 8) ^ ((i & 7) << 4))) = pk;
    }
#pragma unroll
    for (int c = 0; c < 8; ++c) {
      int idx = c * 256 + t;
      int fr = idx >> 3, kc = idx & 7;
      uint4 v = *reinterpret_cast<const uint4*>(Wt + fr * 256 + k0 + kc * 8);
      *reinterpret_cast<uint4*>(Blds + fr * 128 + ((kc * 16) ^ ((fr & 7) << 4))) = v;
    }
    __syncthreads();
#pragma unroll
    for (int kk = 0; kk < 2; ++kk) {
      int kofs = kk * 64 + lk * 16;
      s16x8 afr[4], bfr[4];
#pragma unroll
      for (int mf = 0; mf < 4; ++mf) {
        int ar = mf * 16 + lr;
        afr[mf] = *reinterpret_cast<const s16x8*>(Alds + ar * 128 + (kofs ^ ((ar & 7) << 4)));
      }
#pragma unroll
      for (int nf = 0; nf < 4; ++nf) {
        int br = w * 64 + nf * 16 + lr;
        bfr[nf] = *reinterpret_cast<const s16x8*>(Blds + br * 128 + (kofs ^ ((br & 7) << 4)));
      }
#pragma unroll
      for (int mf = 0; mf < 4; ++mf)
#pragma unroll
        for (int nf = 0; nf < 4; ++nf)
          acc[mf][nf] = __builtin_amdgcn_mfma_f32_16x16x32_bf16(afr[mf], bfr[nf], acc[mf][nf], 0, 0, 0);
    }
  }
  // epilogue: store in k3-ready tiled/swizzled layout
  int tj = blockIdx.x;
#pragma unroll
  for (int mf = 0; mf < 4; ++mf) {
#pragma unroll
    for (int nf = 0; nf < 4; ++nf) {
      int f = w * 64 + nf * 16 + lr;
      int jj = mf * 16 + lk * 4;
      int kc = jj >> 3, sub = (jj >> 2) & 1;
      ushort4 pk;
      pk.x = f2bf(acc[mf][nf][0]);
      pk.y = f2bf(acc[mf][nf][1]);
      pk.z = f2bf(acc[mf][nf][2]);
      pk.w = f2bf(acc[mf][nf][3]);
      *reinterpret_cast<ushort4*>(WhbT + (size_t)tj * 32768 + f * 128 +
                                  ((kc * 16) ^ ((f & 7) << 4)) + sub * 8) = pk;
    }
  }
  // fused s1/s2 from f32 accumulators
  float a1v[4], a2v[4];
#pragma unroll
  for (int nf = 0; nf < 4; ++nf) {
    int f = w * 64 + nf * 16 + lr;
    a1v[nf] = a[f];
    a2v[nf] = a[256 + f];
  }
  float* s1l = (float*)lds;
  float* s2l = s1l + 64;
  __syncthreads();
  if (t < 128) s1l[t] = 0.f;
  __syncthreads();
#pragma unroll
  for (int mf = 0; mf < 4; ++mf) {
#pragma unroll
    for (int r = 0; r < 4; ++r) {
      float p1 = 0.f, p2 = 0.f;
#pragma unroll
      for (int nf = 0; nf < 4; ++nf) {
        p1 += acc[mf][nf][r] * a1v[nf];
        p2 += acc[mf][nf][r] * a2v[nf];
      }
      p1 += __shfl_xor(p1, 1); p1 += __shfl_xor(p1, 2);
      p1 += __shfl_xor(p1, 4); p1 += __shfl_xor(p1, 8);
      p2 += __shfl_xor(p2, 1); p2 += __shfl_xor(p2, 2);
      p2 += __shfl_xor(p2, 4); p2 += __shfl_xor(p2, 8);
      if (lr == 0) {
        atomicAdd(&s1l[mf * 16 + lk * 4 + r], p1);
        atomicAdd(&s2l[mf * 16 + lk * 4 + r], p2);
      }
    }
  }
  __syncthreads();
  if (t < 64) {
    s1g[i0 + t] = s1l[t] * LOG2E;
    s2g[i0 + t] = s2l[t] * LOG2E;
  }
}

// ---------------- k3: BARRIER-FREE fused adj->P(regs)->MFMA ----------------
// 4 waves x 16 rows = M=64/block; grid (128, KSPLIT) = 512 blocks (~3/CU by VGPR).
// B-fragments read directly from tiled WhbT (32 KB/tile = L1-resident, 4-wave shared).
// adj read nontemporal, ping/pong distance-1, issued AFTER B loads (in-order vmcnt safe).
// NO __syncthreads in the loop -> no vmcnt drains; waves free-run the adj stream.
__global__ __launch_bounds__(256) void k3_attn(const float* __restrict__ adj,
                                               const char* __restrict__ WhbT,
                                               const float* __restrict__ s1,
                                               const float* __restrict__ s2,
                                               float* __restrict__ numw,
                                               float* __restrict__ denw) {
  __shared__ float s2l[JBLK];   // 8 KB
  int t = threadIdx.x, w = t >> 6, l = t & 63, lr = l & 15, lk = l >> 4;
  int i0 = blockIdx.x * 64;
  int ks = blockIdx.y;
  int jb = ks * JBLK;
  int lko = lk * 8;

  // stage the s2 slice (pre-scaled by log2e in k1)
  *reinterpret_cast<float4*>(&s2l[t * 8]) = *reinterpret_cast<const float4*>(s2 + jb + t * 8);
  *reinterpret_cast<float4*>(&s2l[t * 8 + 4]) = *reinterpret_cast<const float4*>(s2 + jb + t * 8 + 4);

  int row = i0 + w * 16 + lr;
  const float* arow = adj + (size_t)row * N + jb;
  float s1v = s1[row];

  f32x4 acc[16] = {};
  float ds = 0.f;
  f32x4 ajA[4], ajB[4];

  // prologue: adj tile 0 -> ajA
#pragma unroll
  for (int q = 0; q < 2; ++q) {
    ajA[q]     = ntl4(arow + lko + q * 4);
    ajA[2 + q] = ntl4(arow + 32 + lko + q * 4);
  }
  __syncthreads();   // s2l ready (once; also drains prologue adj)

#define PEL(dst, e, av, sv)                                                    \
  {                                                                            \
    float x = s1v + (sv); x = fmaxf(x, 0.2f * x);                              \
    float p = (av) > 0.f ? exp2f(x) : 0.f;                                     \
    unsigned short us = (unsigned short)((__float_as_uint(p) + 0x8000u) >> 16);\
    ds += bf2f(us); dst[e] = (short)us;                                        \
  }
#define PFRAG(dst, a0, a1, sv0, sv1)                                           \
  PEL(dst, 0, a0.x, sv0.x) PEL(dst, 1, a0.y, sv0.y)                            \
  PEL(dst, 2, a0.z, sv0.z) PEL(dst, 3, a0.w, sv0.w)                            \
  PEL(dst, 4, a1.x, sv1.x) PEL(dst, 5, a1.y, sv1.y)                            \
  PEL(dst, 6, a1.z, sv1.z) PEL(dst, 7, a1.w, sv1.w)

#define BODY(IT, CUR, NXT)                                                     \
  {                                                                            \
    const int it = (IT);                                                       \
    float4 sa0 = *reinterpret_cast<const float4*>(&s2l[it * 64 + lko]);        \
    float4 sb0 = *reinterpret_cast<const float4*>(&s2l[it * 64 + lko + 4]);    \
    float4 sa1 = *reinterpret_cast<const float4*>(&s2l[it * 64 + 32 + lko]);   \
    float4 sb1 = *reinterpret_cast<const float4*>(&s2l[it * 64 + 32 + lko + 4]);\
    s16x8 af0, af1;                                                            \
    PFRAG(af0, CUR[0], CUR[1], sa0, sb0)                                       \
    PFRAG(af1, CUR[2], CUR[3], sa1, sb1)                                       \
    const char* Bt = WhbT + (size_t)(ks * NITER + it) * 32768;                 \
    _Pragma("unroll") for (int kk = 0; kk < 2; ++kk) {                         \
      int kofs = kk * 64 + lk * 16;                                            \
      s16x8 af = kk ? af1 : af0;                                               \
      _Pragma("unroll") for (int nf = 0; nf < 16; ++nf) {                      \
        int br = nf * 16 + lr;                                                 \
        s16x8 bfr = *reinterpret_cast<const s16x8*>(                           \
            Bt + br * 128 + (kofs ^ ((br & 7) << 4)));                         \
        acc[nf] = __builtin_amdgcn_mfma_f32_16x16x32_bf16(af, bfr, acc[nf], 0, 0, 0); \
      }                                                                        \
    }                                                                          \
    if (it + 1 < NITER) {                                                      \
      const float* ap = arow + (it + 1) * 64;                                  \
      _Pragma("unroll") for (int q = 0; q < 2; ++q) {                          \
        NXT[q]     = ntl4(ap + lko + q * 4);                                   \
        NXT[2 + q] = ntl4(ap + 32 + lko + q * 4);                              \
      }                                                                        \
    }                                                                          \
  }

  for (int it2 = 0; it2 < NITER / 2; ++it2) {
    BODY(2 * it2, ajA, ajB);
    BODY(2 * it2 + 1, ajB, ajA);
  }
#undef BODY
#undef PFRAG
#undef PEL

  // denominator: reduce across lk groups (j-partitions of the row)
  ds += __shfl_xor(ds, 16);
  ds += __shfl_xor(ds, 32);
  if (l < 16) denw[(size_t)ks * N + row] = ds;

  // numerator partials
  float* nump = numw + (size_t)ks * N * F;
#pragma unroll
  for (int nf = 0; nf < 16; ++nf) {
#pragma unroll
    for (int r = 0; r < 4; ++r) {
      nump[(size_t)(i0 + w * 16 + lk * 4 + r) * F + nf * 16 + lr] = acc[nf][r];
    }
  }
}

// ---------------- k4: combine K-splits, divide, elu (float4) ----------------
__global__ __launch_bounds__(256) void k4_fin(const float* __restrict__ numw,
                                              const float* __restrict__ denw,
                                              float* __restrict__ out) {
  int idx = (blockIdx.x * 256 + threadIdx.x) * 4;
  int i = idx >> 8;
  float4 sn = {0.f, 0.f, 0.f, 0.f};
  float sd = 0.f;
#pragma unroll
  for (int ksp = 0; ksp < KSPLIT; ++ksp) {
    float4 v = *reinterpret_cast<const float4*>(numw + (size_t)ksp * N * F + idx);
    sn.x += v.x; sn.y += v.y; sn.z += v.z; sn.w += v.w;
    sd += denw[(size_t)ksp * N + i];
  }
  float r = 1.f / sd;
  float4 o;
  float hp;
  hp = sn.x * r; o.x = hp > 0.f ? hp : (__expf(hp) - 1.f);
  hp = sn.y * r; o.y = hp > 0.f ? hp : (__expf(hp) - 1.f);
  hp = sn.z * r; o.z = hp > 0.f ? hp : (__expf(hp) - 1.f);
  hp = sn.w * r; o.w = hp > 0.f ? hp : (__expf(hp) - 1.f);
  *reinterpret_cast<float4*>(out + idx) = o;
}

extern "C" void kernel_launch(void* const* d_in, const int* in_sizes, int n_in,
                              void* d_out, int out_size, void* d_ws, size_t ws_size,
                              hipStream_t stream) {
  const float* h   = (const float*)d_in[0];
  const float* adj = (const float*)d_in[1];
  const float* W   = (const float*)d_in[2];
  const float* a   = (const float*)d_in[3];
  float* out = (float*)d_out;

  char* ws = (char*)d_ws;
  size_t o = 0;
  char* WhbT           = ws + o;                    o += (size_t)4 * 1024 * 1024;    // tiled
  float* s1            = (float*)(ws + o);          o += 32768;
  float* s2            = (float*)(ws + o);          o += 32768;
  float* denw          = (float*)(ws + o);          o += (size_t)KSPLIT * N * 4;     // 128 KB
  unsigned short* Wt   = (unsigned short*)(ws + o); o += 131072;
  float* numw          = (float*)(ws + o);          o += (size_t)KSPLIT * N * F * 4; // 32 MB

  hipLaunchKernelGGL(k0_wt, dim3(256), dim3(256), 0, stream, W, Wt);
  hipLaunchKernelGGL(k1_wh, dim3(N / 64), dim3(256), 0, stream, h, Wt, a, WhbT, s1, s2);
  hipLaunchKernelGGL(k3_attn, dim3(N / 64, KSPLIT), dim3(256), 0, stream,
                     adj, WhbT, s1, s2, numw, denw);
  hipLaunchKernelGGL(k4_fin, dim3(N * F / 1024), dim3(256), 0, stream, numw, denw, out);
}

// Round 9
// 131.500 us; speedup vs baseline: 2.2802x; 2.2802x over previous
//
#include <hip/hip_runtime.h>
#include <hip/hip_bf16.h>

#define N 8192
#define F 256
#define KSPLIT 4
#define JBLK (N / KSPLIT)    // 2048 cols per k3 block
#define NITER (JBLK / 64)    // 32 j-tiles of 64
#define LOG2E 1.4426950408889634f

using s16x8 = __attribute__((ext_vector_type(8))) short;
using f32x4 = __attribute__((ext_vector_type(4))) float;

static __device__ __forceinline__ unsigned short f2bf(float f) {
  unsigned int u = __float_as_uint(f);
  unsigned int r = u + 0x7fffu + ((u >> 16) & 1u);   // RNE
  return (unsigned short)(r >> 16);
}
static __device__ __forceinline__ float bf2f(unsigned short u) {
  return __uint_as_float(((unsigned int)u) << 16);
}
static __device__ __forceinline__ void glds16(const void* g, void* l) {
  __builtin_amdgcn_global_load_lds(
      (const __attribute__((address_space(1))) unsigned int*)g,
      (__attribute__((address_space(3))) unsigned int*)l, 16, 0, 0);
}

// ---------------- k0: Wt[f][k] = bf16(W[k][f]) ----------------
__global__ __launch_bounds__(256) void k0_wt(const float* __restrict__ W,
                                             unsigned short* __restrict__ Wt) {
  int k = blockIdx.x;
  int f = threadIdx.x;
  Wt[f * 256 + k] = f2bf(W[k * 256 + f]);
}

// ---------------- k1: Wh GEMM -> tiled/swizzled WhbT + fused s1,s2 (pre-scaled by log2e) ----
__global__ __launch_bounds__(256) void k1_wh(const float* __restrict__ h,
                                             const unsigned short* __restrict__ Wt,
                                             const float* __restrict__ a,
                                             char* __restrict__ WhbT,
                                             float* __restrict__ s1g,
                                             float* __restrict__ s2g) {
  __shared__ char lds[8192 + 32768];
  char* Alds = lds;
  char* Blds = lds + 8192;
  int t = threadIdx.x;
  int i0 = blockIdx.x * 64;
  int l = t & 63, w = t >> 6;
  int lr = l & 15, lk = l >> 4;
  f32x4 acc[4][4] = {};
  for (int kt = 0; kt < 4; ++kt) {
    int k0 = kt * 64;
    if (kt) __syncthreads();
#pragma unroll
    for (int c = 0; c < 4; ++c) {
      int flat = c * 256 + t;
      int i = flat >> 4, jc = flat & 15;
      float4 v = *reinterpret_cast<const float4*>(h + (size_t)(i0 + i) * 256 + k0 + jc * 4);
      ushort4 pk;
      pk.x = f2bf(v.x); pk.y = f2bf(v.y); pk.z = f2bf(v.z); pk.w = f2bf(v.w);
      *reinterpret_cast<ushort4*>(Alds + i * 128 + ((jc * 8) ^ ((i & 7) << 4))) = pk;
    }
#pragma unroll
    for (int c = 0; c < 8; ++c) {
      int idx = c * 256 + t;
      int fr = idx >> 3, kc = idx & 7;
      uint4 v = *reinterpret_cast<const uint4*>(Wt + fr * 256 + k0 + kc * 8);
      *reinterpret_cast<uint4*>(Blds + fr * 128 + ((kc * 16) ^ ((fr & 7) << 4))) = v;
    }
    __syncthreads();
#pragma unroll
    for (int kk = 0; kk < 2; ++kk) {
      int kofs = kk * 64 + lk * 16;
      s16x8 afr[4], bfr[4];
#pragma unroll
      for (int mf = 0; mf < 4; ++mf) {
        int ar = mf * 16 + lr;
        afr[mf] = *reinterpret_cast<const s16x8*>(Alds + ar * 128 + (kofs ^ ((ar & 7) << 4)));
      }
#pragma unroll
      for (int nf = 0; nf < 4; ++nf) {
        int br = w * 64 + nf * 16 + lr;
        bfr[nf] = *reinterpret_cast<const s16x8*>(Blds + br * 128 + (kofs ^ ((br & 7) << 4)));
      }
#pragma unroll
      for (int mf = 0; mf < 4; ++mf)
#pragma unroll
        for (int nf = 0; nf < 4; ++nf)
          acc[mf][nf] = __builtin_amdgcn_mfma_f32_16x16x32_bf16(afr[mf], bfr[nf], acc[mf][nf], 0, 0, 0);
    }
  }
  int tj = blockIdx.x;
#pragma unroll
  for (int mf = 0; mf < 4; ++mf) {
#pragma unroll
    for (int nf = 0; nf < 4; ++nf) {
      int f = w * 64 + nf * 16 + lr;
      int jj = mf * 16 + lk * 4;
      int kc = jj >> 3, sub = (jj >> 2) & 1;
      ushort4 pk;
      pk.x = f2bf(acc[mf][nf][0]);
      pk.y = f2bf(acc[mf][nf][1]);
      pk.z = f2bf(acc[mf][nf][2]);
      pk.w = f2bf(acc[mf][nf][3]);
      *reinterpret_cast<ushort4*>(WhbT + (size_t)tj * 32768 + f * 128 +
                                  ((kc * 16) ^ ((f & 7) << 4)) + sub * 8) = pk;
    }
  }
  float a1v[4], a2v[4];
#pragma unroll
  for (int nf = 0; nf < 4; ++nf) {
    int f = w * 64 + nf * 16 + lr;
    a1v[nf] = a[f];
    a2v[nf] = a[256 + f];
  }
  float* s1l = (float*)lds;
  float* s2l = s1l + 64;
  __syncthreads();
  if (t < 128) s1l[t] = 0.f;
  __syncthreads();
#pragma unroll
  for (int mf = 0; mf < 4; ++mf) {
#pragma unroll
    for (int r = 0; r < 4; ++r) {
      float p1 = 0.f, p2 = 0.f;
#pragma unroll
      for (int nf = 0; nf < 4; ++nf) {
        p1 += acc[mf][nf][r] * a1v[nf];
        p2 += acc[mf][nf][r] * a2v[nf];
      }
      p1 += __shfl_xor(p1, 1); p1 += __shfl_xor(p1, 2);
      p1 += __shfl_xor(p1, 4); p1 += __shfl_xor(p1, 8);
      p2 += __shfl_xor(p2, 1); p2 += __shfl_xor(p2, 2);
      p2 += __shfl_xor(p2, 4); p2 += __shfl_xor(p2, 8);
      if (lr == 0) {
        atomicAdd(&s1l[mf * 16 + lk * 4 + r], p1);
        atomicAdd(&s2l[mf * 16 + lk * 4 + r], p2);
      }
    }
  }
  __syncthreads();
  if (t < 64) {
    s1g[i0 + t] = s1l[t] * LOG2E;
    s2g[i0 + t] = s2l[t] * LOG2E;
  }
}

// ---------------- k3: fused adj(glds)->P(regs)->MFMA, counted-vmcnt pipeline ----------------
// 512 thr (8 waves x 16 rows = M=128); grid (64, KSPLIT) = 256 blocks = 1/CU.
// Per tile: 32KB adj + 32KB B staged via global_load_lds (8 glds/wave, 0 VGPR),
// double-buffered; vmcnt(8) counted (tile t+1 stays in flight across barriers).
// adj LDS reads conflict-free via pre-swizzled glds SOURCE (granule G -> G^(r&7)).
__global__ __launch_bounds__(512) void k3_attn(const float* __restrict__ adj,
                                               const char* __restrict__ WhbT,
                                               const float* __restrict__ s1,
                                               const float* __restrict__ s2,
                                               float* __restrict__ numw,
                                               float* __restrict__ denw) {
  __shared__ char lds[2 * 32768 + 2 * 32768 + 8192];   // adj dbuf | B dbuf | s2l
  char* Abase = lds;
  char* Bbase = lds + 65536;
  float* s2l = (float*)(lds + 131072);
  int t = threadIdx.x, w = t >> 6, l = t & 63, lr = l & 15, lk = l >> 4;
  int i0 = blockIdx.x * 128;
  int ks = blockIdx.y;
  int jb = ks * JBLK;
  int r = w * 16 + lr;           // local row; r&7 == lr&7
  int row = i0 + r;
  float s1v = s1[row];

  // stage s2 slice (pre-scaled) once
  *reinterpret_cast<float4*>(&s2l[t * 4]) = *reinterpret_cast<const float4*>(s2 + jb + t * 4);

  f32x4 acc[16] = {};
  float ds = 0.f;

#define STAGE(tile, buf)                                                        \
  {                                                                             \
    const char* gB = WhbT + (size_t)(ks * NITER + (tile)) * 32768 + w * 4096;   \
    char* lB = Bbase + (buf) * 32768 + w * 4096;                                \
    _Pragma("unroll") for (int c = 0; c < 4; ++c)                               \
        glds16(gB + c * 1024 + l * 16, lB + c * 1024);                          \
    char* lA = Abase + (buf) * 32768 + w * 4096;                                \
    _Pragma("unroll") for (int c = 0; c < 4; ++c) {                             \
      int rloc = w * 16 + c * 4 + (l >> 4);                                     \
      const float* srcA = adj + (size_t)(i0 + rloc) * N + jb + (tile) * 64 +    \
                          (((l & 15) ^ (rloc & 7)) << 2);                       \
      glds16(srcA, lA + c * 1024);                                              \
    }                                                                           \
  }

  STAGE(0, 0);
  __syncthreads();   // s2l ready; prologue glds drained (once)

  for (int it = 0; it < NITER; ++it) {
    int cb = it & 1;
    bool pf = (it + 1) < NITER;
    if (pf) {
      STAGE(it + 1, cb ^ 1);
      asm volatile("s_waitcnt vmcnt(8)" ::: "memory");   // tile it landed; it+1 in flight
    } else {
      asm volatile("s_waitcnt vmcnt(0)" ::: "memory");
    }
    __builtin_amdgcn_s_barrier();                        // all waves: tile it staged

    // ---- adj -> P -> A-fragments (LDS reads, swizzle-corrected) ----
    const char* At = Abase + cb * 32768 + r * 256;
    s16x8 afr[2];
#pragma unroll
    for (int kk = 0; kk < 2; ++kk) {
      int G0 = kk * 8 + lk * 2;
      f32x4 av0 = *reinterpret_cast<const f32x4*>(At + ((G0 ^ (r & 7)) << 4));
      f32x4 av1 = *reinterpret_cast<const f32x4*>(At + (((G0 + 1) ^ (r & 7)) << 4));
      const float* sp = &s2l[it * 64 + kk * 32 + lk * 8];
      float4 sv0 = *reinterpret_cast<const float4*>(sp);
      float4 sv1 = *reinterpret_cast<const float4*>(sp + 4);
      s16x8 af;
#define PEL(e, av, sv)                                                          \
      {                                                                         \
        float x = s1v + (sv); x = fmaxf(x, 0.2f * x);                           \
        float p = (av) > 0.f ? exp2f(x) : 0.f;                                  \
        unsigned short us = (unsigned short)((__float_as_uint(p) + 0x8000u) >> 16); \
        ds += bf2f(us); af[e] = (short)us;                                      \
      }
      PEL(0, av0[0], sv0.x) PEL(1, av0[1], sv0.y) PEL(2, av0[2], sv0.z) PEL(3, av0[3], sv0.w)
      PEL(4, av1[0], sv1.x) PEL(5, av1[1], sv1.y) PEL(6, av1[2], sv1.z) PEL(7, av1[3], sv1.w)
#undef PEL
      afr[kk] = af;
    }
    // ---- MFMA: 2 kk x 16 nf ----
    const char* Bt = Bbase + cb * 32768;
#pragma unroll
    for (int kk = 0; kk < 2; ++kk) {
      int kofs = kk * 64 + lk * 16;
#pragma unroll
      for (int nf = 0; nf < 16; ++nf) {
        int br = nf * 16 + lr;
        s16x8 bfr = *reinterpret_cast<const s16x8*>(Bt + br * 128 + (kofs ^ ((br & 7) << 4)));
        acc[nf] = __builtin_amdgcn_mfma_f32_16x16x32_bf16(afr[kk], bfr, acc[nf], 0, 0, 0);
      }
    }
    asm volatile("s_waitcnt lgkmcnt(0)" ::: "memory");
    __builtin_amdgcn_s_barrier();                        // reads done; next stage may overwrite
  }
#undef STAGE

  // denominator: reduce across lk groups (j-partitions of the row)
  ds += __shfl_xor(ds, 16);
  ds += __shfl_xor(ds, 32);
  if (l < 16) denw[(size_t)ks * N + row] = ds;

  // numerator partials
  float* nump = numw + (size_t)ks * N * F;
#pragma unroll
  for (int nf = 0; nf < 16; ++nf) {
#pragma unroll
    for (int rr = 0; rr < 4; ++rr) {
      nump[(size_t)(i0 + w * 16 + lk * 4 + rr) * F + nf * 16 + lr] = acc[nf][rr];
    }
  }
}

// ---------------- k4: combine K-splits, divide, elu (float4) ----------------
__global__ __launch_bounds__(256) void k4_fin(const float* __restrict__ numw,
                                              const float* __restrict__ denw,
                                              float* __restrict__ out) {
  int idx = (blockIdx.x * 256 + threadIdx.x) * 4;
  int i = idx >> 8;
  float4 sn = {0.f, 0.f, 0.f, 0.f};
  float sd = 0.f;
#pragma unroll
  for (int ksp = 0; ksp < KSPLIT; ++ksp) {
    float4 v = *reinterpret_cast<const float4*>(numw + (size_t)ksp * N * F + idx);
    sn.x += v.x; sn.y += v.y; sn.z += v.z; sn.w += v.w;
    sd += denw[(size_t)ksp * N + i];
  }
  float r = 1.f / sd;
  float4 o;
  float hp;
  hp = sn.x * r; o.x = hp > 0.f ? hp : (__expf(hp) - 1.f);
  hp = sn.y * r; o.y = hp > 0.f ? hp : (__expf(hp) - 1.f);
  hp = sn.z * r; o.z = hp > 0.f ? hp : (__expf(hp) - 1.f);
  hp = sn.w * r; o.w = hp > 0.f ? hp : (__expf(hp) - 1.f);
  *reinterpret_cast<float4*>(out + idx) = o;
}

extern "C" void kernel_launch(void* const* d_in, const int* in_sizes, int n_in,
                              void* d_out, int out_size, void* d_ws, size_t ws_size,
                              hipStream_t stream) {
  const float* h   = (const float*)d_in[0];
  const float* adj = (const float*)d_in[1];
  const float* W   = (const float*)d_in[2];
  const float* a   = (const float*)d_in[3];
  float* out = (float*)d_out;

  char* ws = (char*)d_ws;
  size_t o = 0;
  char* WhbT           = ws + o;                    o += (size_t)4 * 1024 * 1024;    // tiled
  float* s1            = (float*)(ws + o);          o += 32768;
  float* s2            = (float*)(ws + o);          o += 32768;
  float* denw          = (float*)(ws + o);          o += (size_t)KSPLIT * N * 4;     // 128 KB
  unsigned short* Wt   = (unsigned short*)(ws + o); o += 131072;
  float* numw          = (float*)(ws + o);          o += (size_t)KSPLIT * N * F * 4; // 32 MB

  hipLaunchKernelGGL(k0_wt, dim3(256), dim3(256), 0, stream, W, Wt);
  hipLaunchKernelGGL(k1_wh, dim3(N / 64), dim3(256), 0, stream, h, Wt, a, WhbT, s1, s2);
  hipLaunchKernelGGL(k3_attn, dim3(N / 128, KSPLIT), dim3(512), 0, stream,
                     adj, WhbT, s1, s2, numw, denw);
  hipLaunchKernelGGL(k4_fin, dim3(N * F / 1024), dim3(256), 0, stream, numw, denw, out);
}